// Round 6
// baseline (634.634 us; speedup 1.0000x reference)
//
#include <hip/hip_runtime.h>

typedef __bf16 bf16x8 __attribute__((ext_vector_type(8)));
typedef float floatx4 __attribute__((ext_vector_type(4)));

// Sizes (fixed): B=4, P=2048, DIM=1024, H=16, HKV=8, D=64
#define BSZ 4
#define SEQ 2048
#define DIM 1024
#define NH 16
#define NKV 8
#define HD 64

// ---------------------------------------------------------------------------
// Kernel 1: fused QKV projection.  x[8192][1024](f32) @ [Wq|Wk|Wv](f32)
// -> q,k,v workspace (bf16).  64x64 tile, 4 waves, K-step 32.
// q scaled by D^-0.5 = 0.125 (exact pow2), stored [B][H][P][D];
// k,v stored [B][HKV][P][D].
// ---------------------------------------------------------------------------
__global__ __launch_bounds__(256) void qkv_gemm(
    const float* __restrict__ x,
    const float* __restrict__ Wq, const float* __restrict__ Wk,
    const float* __restrict__ Wv,
    __bf16* __restrict__ qw, __bf16* __restrict__ kw, __bf16* __restrict__ vw)
{
    __shared__ __align__(16) __bf16 As[64 * 40];   // [m][kk], stride 40 (pad)
    __shared__ __align__(16) __bf16 Bs[64 * 40];   // [c][kk] transposed

    const int m0 = blockIdx.y * 64;
    const int c0 = blockIdx.x * 64;

    const float* W; int ldn, cb;
    if (c0 < 1024)      { W = Wq; ldn = 1024; cb = c0; }
    else if (c0 < 1536) { W = Wk; ldn = 512;  cb = c0 - 1024; }
    else                { W = Wv; ldn = 512;  cb = c0 - 1536; }

    const int tid  = threadIdx.x;
    const int lane = tid & 63, wv = tid >> 6;
    const int l16  = lane & 15, quad = lane >> 4;

    floatx4 acc[4] = {};

    for (int k0 = 0; k0 < 1024; k0 += 32) {
        // stage A 64x32 (two float4 loads -> bf16x8 store)
        {
            int m = tid >> 2, kk = (tid & 3) << 3;
            const float* src = &x[(size_t)(m0 + m) * 1024 + k0 + kk];
            float4 f0 = *(const float4*)src;
            float4 f1 = *(const float4*)(src + 4);
            bf16x8 a;
            a[0] = (__bf16)f0.x; a[1] = (__bf16)f0.y;
            a[2] = (__bf16)f0.z; a[3] = (__bf16)f0.w;
            a[4] = (__bf16)f1.x; a[5] = (__bf16)f1.y;
            a[6] = (__bf16)f1.z; a[7] = (__bf16)f1.w;
            *(bf16x8*)&As[m * 40 + kk] = a;
        }
        // stage B 32x64 transposed into [c][kk]
        {
            int kk = tid >> 3, c = (tid & 7) << 3;
            const float* wsrc = &W[(size_t)(k0 + kk) * ldn + cb + c];
            float4 w0 = *(const float4*)wsrc;
            float4 w1 = *(const float4*)(wsrc + 4);
            Bs[(c + 0) * 40 + kk] = (__bf16)w0.x;
            Bs[(c + 1) * 40 + kk] = (__bf16)w0.y;
            Bs[(c + 2) * 40 + kk] = (__bf16)w0.z;
            Bs[(c + 3) * 40 + kk] = (__bf16)w0.w;
            Bs[(c + 4) * 40 + kk] = (__bf16)w1.x;
            Bs[(c + 5) * 40 + kk] = (__bf16)w1.y;
            Bs[(c + 6) * 40 + kk] = (__bf16)w1.z;
            Bs[(c + 7) * 40 + kk] = (__bf16)w1.w;
        }
        __syncthreads();

        bf16x8 af = *(bf16x8*)&As[(16 * wv + l16) * 40 + quad * 8];
#pragma unroll
        for (int t = 0; t < 4; ++t) {
            bf16x8 bfr = *(bf16x8*)&Bs[(16 * t + l16) * 40 + quad * 8];
            acc[t] = __builtin_amdgcn_mfma_f32_16x16x32_bf16(af, bfr, acc[t], 0, 0, 0);
        }
        __syncthreads();
    }

    // epilogue: C/D layout col=lane&15, row=quad*4+r
#pragma unroll
    for (int t = 0; t < 4; ++t) {
        int c = c0 + 16 * t + l16;
#pragma unroll
        for (int r = 0; r < 4; ++r) {
            int m  = m0 + 16 * wv + quad * 4 + r;
            int bb = m >> 11, p = m & 2047;
            float val = acc[t][r];
            if (c < 1024) {
                int h = c >> 6, d = c & 63;
                qw[(((size_t)bb * NH + h) * SEQ + p) * HD + d] = (__bf16)(val * 0.125f);
            } else if (c < 1536) {
                int cc = c - 1024; int hh = cc >> 6, d = cc & 63;
                kw[(((size_t)bb * NKV + hh) * SEQ + p) * HD + d] = (__bf16)val;
            } else {
                int cc = c - 1536; int hh = cc >> 6, d = cc & 63;
                vw[(((size_t)bb * NKV + hh) * SEQ + p) * HD + d] = (__bf16)val;
            }
        }
    }
}

// ---------------------------------------------------------------------------
// Kernel 2: per-(b,kv) sqrt(sum of squares of k) -> mags_b[b*8+kv]
// ---------------------------------------------------------------------------
__global__ __launch_bounds__(256) void ksumsq(const __bf16* __restrict__ kw,
                                              float* __restrict__ mags_b)
{
    const int blk = blockIdx.x;  // b*8+kv
    const __bf16* base = kw + (size_t)blk * (SEQ * HD);
    const int tid = threadIdx.x;

    float s = 0.f;
    for (int i = tid * 8; i < SEQ * HD; i += 256 * 8) {
        bf16x8 vv = *(const bf16x8*)&base[i];
#pragma unroll
        for (int j = 0; j < 8; ++j) { float f = (float)vv[j]; s += f * f; }
    }
#pragma unroll
    for (int off = 1; off < 64; off <<= 1) s += __shfl_xor(s, off, 64);

    __shared__ float red[4];
    if ((tid & 63) == 0) red[tid >> 6] = s;
    __syncthreads();
    if (tid == 0) mags_b[blk] = sqrtf(red[0] + red[1] + red[2] + red[3]);
}

// ---------------------------------------------------------------------------
// Kernel 3: ratios + kv_id (replica of _ratios + searchsorted-right)
// ---------------------------------------------------------------------------
__global__ void ratios_kernel(const float* __restrict__ mags_b,
                              const float* __restrict__ cache,
                              int* __restrict__ kv_id)
{
    if (threadIdx.x != 0 || blockIdx.x != 0) return;
    float diff[8], sum = 0.f;
    for (int j = 0; j < 8; ++j) {
        float mag = mags_b[j] + mags_b[8 + j] + mags_b[16 + j] + mags_b[24 + j];
        diff[j] = fabsf(cache[j] - mag);
        sum += diff[j];
    }
    int r[8], s = 0;
    for (int j = 0; j < 8; ++j) {
        r[j] = (int)rintf(diff[j] / sum * 16.0f);  // round half to even (jnp.round)
        s += r[j];
    }
    while (s > 16) {  // argmax (first occurrence) -= 1
        int jm = 0;
        for (int j = 1; j < 8; ++j) if (r[j] > r[jm]) jm = j;
        r[jm]--; s--;
    }
    while (s < 16) {  // argmin (first occurrence) += 1
        int jm = 0;
        for (int j = 1; j < 8; ++j) if (r[j] < r[jm]) jm = j;
        r[jm]++; s++;
    }
    int cum[8], c = 0;
    for (int j = 0; j < 8; ++j) { c += r[j]; cum[j] = c; }
    for (int h = 0; h < 16; ++h) {
        int j = 0;
        while (j < 7 && cum[j] <= h) j++;  // searchsorted side='right'
        kv_id[h] = j;
    }
}

// ---------------------------------------------------------------------------
// Kernel 4: flash attention (online softmax).  Block = 4 waves, 64 Q rows.
// grid = (P/64, B*H).  Loops over 32 key-blocks of 64.
// Output written [B][P][H][D] (row-major DIM) for the projection GEMM.
// ---------------------------------------------------------------------------
__global__ __launch_bounds__(256) void attn_kernel(
    const __bf16* __restrict__ qw, const __bf16* __restrict__ kw,
    const __bf16* __restrict__ vw, const int* __restrict__ kv_id,
    __bf16* __restrict__ attn_out)
{
    __shared__ __align__(16) __bf16 Kt[64 * 72];       // [key][d], pad 72
    __shared__ __align__(16) __bf16 VT[64 * 72];       // [d][key]
    __shared__ __align__(16) __bf16 Pl[4 * 16 * 72];   // per-wave P, [row][key]

    const int bh = blockIdx.y;           // 0..63
    const int b = bh >> 4, h = bh & 15;
    const int q0 = blockIdx.x * 64;
    const int kv = kv_id[h];

    const __bf16* Kg = kw + ((size_t)(b * NKV + kv) * SEQ) * HD;
    const __bf16* Vg = vw + ((size_t)(b * NKV + kv) * SEQ) * HD;
    const __bf16* Qg = qw + ((size_t)(b * NH + h) * SEQ + q0) * HD;

    const int tid  = threadIdx.x;
    const int lane = tid & 63, wv = tid >> 6;
    const int l16  = lane & 15, quad = lane >> 4;

    // Q fragments (A-layout: A[m=lane&15][k=quad*8+j]), two 32-k steps over D=64
    bf16x8 qf0 = *(const bf16x8*)&Qg[(size_t)(16 * wv + l16) * HD + quad * 8];
    bf16x8 qf1 = *(const bf16x8*)&Qg[(size_t)(16 * wv + l16) * HD + 32 + quad * 8];

    float m_run[4], l_run[4];
    floatx4 o[4] = {};
#pragma unroll
    for (int r = 0; r < 4; ++r) { m_run[r] = -1e30f; l_run[r] = 0.f; }

    for (int kb = 0; kb < 32; ++kb) {
        // stage K [key][d] and V transposed [d][key]
        {
            int key = tid >> 2, d0 = (tid & 3) << 4;
            const __bf16* src = &Kg[((size_t)kb * 64 + key) * HD + d0];
            *(bf16x8*)&Kt[key * 72 + d0]     = *(const bf16x8*)src;
            *(bf16x8*)&Kt[key * 72 + d0 + 8] = *(const bf16x8*)(src + 8);
            const __bf16* vsrc = &Vg[((size_t)kb * 64 + key) * HD + d0];
            bf16x8 v0 = *(const bf16x8*)vsrc;
            bf16x8 v1 = *(const bf16x8*)(vsrc + 8);
#pragma unroll
            for (int j = 0; j < 8; ++j) {
                VT[(d0 + j) * 72 + key]     = v0[j];
                VT[(d0 + 8 + j) * 72 + key] = v1[j];
            }
        }
        __syncthreads();

        // S = Q K^T  (16 q-rows x 64 keys per wave)
        floatx4 sacc[4] = {};
#pragma unroll
        for (int t = 0; t < 4; ++t) {
            bf16x8 kf0 = *(bf16x8*)&Kt[(16 * t + l16) * 72 + quad * 8];
            bf16x8 kf1 = *(bf16x8*)&Kt[(16 * t + l16) * 72 + 32 + quad * 8];
            sacc[t] = __builtin_amdgcn_mfma_f32_16x16x32_bf16(qf0, kf0, sacc[t], 0, 0, 0);
            sacc[t] = __builtin_amdgcn_mfma_f32_16x16x32_bf16(qf1, kf1, sacc[t], 0, 0, 0);
        }

        // online softmax; C-layout: row = quad*4+r, col = 16t + l16.
        // Clamp is inert for valid scores (|s| <~ 10) and kills stray NaN/Inf.
        float p[4][4];
#pragma unroll
        for (int r = 0; r < 4; ++r) {
#pragma unroll
            for (int t = 0; t < 4; ++t)
                p[t][r] = fminf(fmaxf(sacc[t][r], -60.f), 60.f);
            float mx = fmaxf(fmaxf(p[0][r], p[1][r]), fmaxf(p[2][r], p[3][r]));
#pragma unroll
            for (int off = 1; off < 16; off <<= 1)
                mx = fmaxf(mx, __shfl_xor(mx, off, 64));
            float m_new = fmaxf(m_run[r], mx);
            float alpha = __expf(m_run[r] - m_new);
            float rs = 0.f;
#pragma unroll
            for (int t = 0; t < 4; ++t) { p[t][r] = __expf(p[t][r] - m_new); rs += p[t][r]; }
#pragma unroll
            for (int off = 1; off < 16; off <<= 1)
                rs += __shfl_xor(rs, off, 64);
            l_run[r] = l_run[r] * alpha + rs;
            m_run[r] = m_new;
#pragma unroll
            for (int t = 0; t < 4; ++t) o[t][r] *= alpha;
        }

        // P (C-layout) -> LDS -> A-layout for PV
        __bf16* Pw = &Pl[wv * 16 * 72];
#pragma unroll
        for (int r = 0; r < 4; ++r)
#pragma unroll
            for (int t = 0; t < 4; ++t)
                Pw[(quad * 4 + r) * 72 + 16 * t + l16] = (__bf16)p[t][r];
        __syncthreads();

        // O += P V
        bf16x8 a0 = *(bf16x8*)&Pw[l16 * 72 + quad * 8];
        bf16x8 a1 = *(bf16x8*)&Pw[l16 * 72 + 32 + quad * 8];
#pragma unroll
        for (int dt = 0; dt < 4; ++dt) {
            bf16x8 b0 = *(bf16x8*)&VT[(16 * dt + l16) * 72 + quad * 8];
            bf16x8 b1 = *(bf16x8*)&VT[(16 * dt + l16) * 72 + 32 + quad * 8];
            o[dt] = __builtin_amdgcn_mfma_f32_16x16x32_bf16(a0, b0, o[dt], 0, 0, 0);
            o[dt] = __builtin_amdgcn_mfma_f32_16x16x32_bf16(a1, b1, o[dt], 0, 0, 0);
        }
        __syncthreads();
    }

    // epilogue: divide by l, store [B][P][H][D]
#pragma unroll
    for (int r = 0; r < 4; ++r) {
        float inv = 1.f / l_run[r];
        int p_ = q0 + 16 * wv + quad * 4 + r;
#pragma unroll
        for (int dt = 0; dt < 4; ++dt) {
            int d = 16 * dt + l16;
            attn_out[(((size_t)b * SEQ + p_) * NH + h) * HD + d] = (__bf16)(o[dt][r] * inv);
        }
    }
}

// ---------------------------------------------------------------------------
// Kernel 5: output projection  attn[8192][1024](bf16) @ Wp(f32) + bp(f32)
// -> out (FLOAT32 — the reference's output dtype)
// ---------------------------------------------------------------------------
__global__ __launch_bounds__(256) void proj_gemm(
    const __bf16* __restrict__ A, const float* __restrict__ Wp,
    const float* __restrict__ bp, float* __restrict__ out)
{
    __shared__ __align__(16) __bf16 As[64 * 40];
    __shared__ __align__(16) __bf16 Bs[64 * 40];

    const int m0 = blockIdx.y * 64, c0 = blockIdx.x * 64;
    const int tid = threadIdx.x, lane = tid & 63, wv = tid >> 6;
    const int l16 = lane & 15, quad = lane >> 4;

    floatx4 acc[4] = {};

    for (int k0 = 0; k0 < 1024; k0 += 32) {
        {
            int m = tid >> 2, kk = (tid & 3) << 3;
            *(bf16x8*)&As[m * 40 + kk] =
                *(const bf16x8*)&A[(size_t)(m0 + m) * 1024 + k0 + kk];
        }
        {
            int kk = tid >> 3, c = (tid & 7) << 3;
            const float* wsrc = &Wp[(size_t)(k0 + kk) * 1024 + c0 + c];
            float4 w0 = *(const float4*)wsrc;
            float4 w1 = *(const float4*)(wsrc + 4);
            Bs[(c + 0) * 40 + kk] = (__bf16)w0.x;
            Bs[(c + 1) * 40 + kk] = (__bf16)w0.y;
            Bs[(c + 2) * 40 + kk] = (__bf16)w0.z;
            Bs[(c + 3) * 40 + kk] = (__bf16)w0.w;
            Bs[(c + 4) * 40 + kk] = (__bf16)w1.x;
            Bs[(c + 5) * 40 + kk] = (__bf16)w1.y;
            Bs[(c + 6) * 40 + kk] = (__bf16)w1.z;
            Bs[(c + 7) * 40 + kk] = (__bf16)w1.w;
        }
        __syncthreads();

        bf16x8 af = *(bf16x8*)&As[(16 * wv + l16) * 40 + quad * 8];
#pragma unroll
        for (int t = 0; t < 4; ++t) {
            bf16x8 bfr = *(bf16x8*)&Bs[(16 * t + l16) * 40 + quad * 8];
            acc[t] = __builtin_amdgcn_mfma_f32_16x16x32_bf16(af, bfr, acc[t], 0, 0, 0);
        }
        __syncthreads();
    }

#pragma unroll
    for (int t = 0; t < 4; ++t) {
        int c = c0 + 16 * t + l16;
        float bias = bp[c];
#pragma unroll
        for (int r = 0; r < 4; ++r) {
            int m = m0 + 16 * wv + quad * 4 + r;
            out[(size_t)m * 1024 + c] = acc[t][r] + bias;   // fp32 store
        }
    }
}

// ---------------------------------------------------------------------------
extern "C" void kernel_launch(void* const* d_in, const int* in_sizes, int n_in,
                              void* d_out, int out_size, void* d_ws, size_t ws_size,
                              hipStream_t stream)
{
    const float* x     = (const float*)d_in[0];
    const float* Wq    = (const float*)d_in[1];
    const float* Wk    = (const float*)d_in[2];
    const float* Wv    = (const float*)d_in[3];
    const float* Wp    = (const float*)d_in[4];
    const float* bp    = (const float*)d_in[5];
    const float* cache = (const float*)d_in[6];
    float* outp = (float*)d_out;   // reference output dtype is float32

    __bf16* ws = (__bf16*)d_ws;
    __bf16* qw = ws;                                   // [B][H][P][D]
    __bf16* kw = qw + (size_t)BSZ * NH * SEQ * HD;     // [B][HKV][P][D]
    __bf16* vw = kw + (size_t)BSZ * NKV * SEQ * HD;    // [B][HKV][P][D]
    __bf16* at = vw + (size_t)BSZ * NKV * SEQ * HD;    // [B][P][H*D]
    float* mags_b = (float*)(at + (size_t)BSZ * NH * SEQ * HD);  // 32 floats
    int*   kv_id  = (int*)(mags_b + 32);                          // 16 ints

    qkv_gemm<<<dim3(32, 128), 256, 0, stream>>>(x, Wq, Wk, Wv, qw, kw, vw);
    ksumsq<<<32, 256, 0, stream>>>(kw, mags_b);
    ratios_kernel<<<1, 64, 0, stream>>>(mags_b, cache, kv_id);
    attn_kernel<<<dim3(32, 64), 256, 0, stream>>>(qw, kw, vw, kv_id, at);
    proj_gemm<<<dim3(16, 128), 256, 0, stream>>>(at, Wp, bp, outp);
}

// Round 7
// 514.964 us; speedup vs baseline: 1.2324x; 1.2324x over previous
//
#include <hip/hip_runtime.h>

typedef __bf16 bf16x8 __attribute__((ext_vector_type(8)));
typedef float floatx4 __attribute__((ext_vector_type(4)));

// Sizes (fixed): B=4, P=2048, DIM=1024, H=16, HKV=8, D=64
#define BSZ 4
#define SEQ 2048
#define DIM 1024
#define NH 16
#define NKV 8
#define HD 64

// ---------------------------------------------------------------------------
// Kernel 1: fused QKV projection.  x[8192][1024](f32) @ [Wq|Wk|Wv](f32)
// -> q,k (bf16, [B][H(KV)][P][D]) and v TRANSPOSED (bf16, [B][HKV][D][P])
// so attention can stage V^T with vector copies (kills 4-way LDS conflicts).
// q scaled by D^-0.5 = 0.125 (exact pow2).
// ---------------------------------------------------------------------------
__global__ __launch_bounds__(256) void qkv_gemm(
    const float* __restrict__ x,
    const float* __restrict__ Wq, const float* __restrict__ Wk,
    const float* __restrict__ Wv,
    __bf16* __restrict__ qw, __bf16* __restrict__ kw, __bf16* __restrict__ vw)
{
    __shared__ __align__(16) __bf16 As[64 * 40];   // [m][kk], stride 40 (pad)
    __shared__ __align__(16) __bf16 Bs[64 * 40];   // [c][kk] transposed

    const int m0 = blockIdx.y * 64;
    const int c0 = blockIdx.x * 64;

    const float* W; int ldn, cb;
    if (c0 < 1024)      { W = Wq; ldn = 1024; cb = c0; }
    else if (c0 < 1536) { W = Wk; ldn = 512;  cb = c0 - 1024; }
    else                { W = Wv; ldn = 512;  cb = c0 - 1536; }

    const int tid  = threadIdx.x;
    const int lane = tid & 63, wv = tid >> 6;
    const int l16  = lane & 15, quad = lane >> 4;

    floatx4 acc[4] = {};

    for (int k0 = 0; k0 < 1024; k0 += 32) {
        // stage A 64x32 (two float4 loads -> bf16x8 store)
        {
            int m = tid >> 2, kk = (tid & 3) << 3;
            const float* src = &x[(size_t)(m0 + m) * 1024 + k0 + kk];
            float4 f0 = *(const float4*)src;
            float4 f1 = *(const float4*)(src + 4);
            bf16x8 a;
            a[0] = (__bf16)f0.x; a[1] = (__bf16)f0.y;
            a[2] = (__bf16)f0.z; a[3] = (__bf16)f0.w;
            a[4] = (__bf16)f1.x; a[5] = (__bf16)f1.y;
            a[6] = (__bf16)f1.z; a[7] = (__bf16)f1.w;
            *(bf16x8*)&As[m * 40 + kk] = a;
        }
        // stage B 32x64 transposed into [c][kk]
        {
            int kk = tid >> 3, c = (tid & 7) << 3;
            const float* wsrc = &W[(size_t)(k0 + kk) * ldn + cb + c];
            float4 w0 = *(const float4*)wsrc;
            float4 w1 = *(const float4*)(wsrc + 4);
            Bs[(c + 0) * 40 + kk] = (__bf16)w0.x;
            Bs[(c + 1) * 40 + kk] = (__bf16)w0.y;
            Bs[(c + 2) * 40 + kk] = (__bf16)w0.z;
            Bs[(c + 3) * 40 + kk] = (__bf16)w0.w;
            Bs[(c + 4) * 40 + kk] = (__bf16)w1.x;
            Bs[(c + 5) * 40 + kk] = (__bf16)w1.y;
            Bs[(c + 6) * 40 + kk] = (__bf16)w1.z;
            Bs[(c + 7) * 40 + kk] = (__bf16)w1.w;
        }
        __syncthreads();

        bf16x8 af = *(bf16x8*)&As[(16 * wv + l16) * 40 + quad * 8];
#pragma unroll
        for (int t = 0; t < 4; ++t) {
            bf16x8 bfr = *(bf16x8*)&Bs[(16 * t + l16) * 40 + quad * 8];
            acc[t] = __builtin_amdgcn_mfma_f32_16x16x32_bf16(af, bfr, acc[t], 0, 0, 0);
        }
        __syncthreads();
    }

    // epilogue: C/D layout col=lane&15, row=quad*4+r
#pragma unroll
    for (int t = 0; t < 4; ++t) {
        int c = c0 + 16 * t + l16;
#pragma unroll
        for (int r = 0; r < 4; ++r) {
            int m  = m0 + 16 * wv + quad * 4 + r;
            int bb = m >> 11, p = m & 2047;
            float val = acc[t][r];
            if (c < 1024) {
                int h = c >> 6, d = c & 63;
                qw[(((size_t)bb * NH + h) * SEQ + p) * HD + d] = (__bf16)(val * 0.125f);
            } else if (c < 1536) {
                int cc = c - 1024; int hh = cc >> 6, d = cc & 63;
                kw[(((size_t)bb * NKV + hh) * SEQ + p) * HD + d] = (__bf16)val;
            } else {
                int cc = c - 1536; int hh = cc >> 6, d = cc & 63;
                // V stored transposed: [B][HKV][D][P]
                vw[(((size_t)bb * NKV + hh) * HD + d) * SEQ + p] = (__bf16)val;
            }
        }
    }
}

// ---------------------------------------------------------------------------
// Kernel 2: per-(b,kv) sqrt(sum of squares of k) -> mags_b[b*8+kv]
// ---------------------------------------------------------------------------
__global__ __launch_bounds__(256) void ksumsq(const __bf16* __restrict__ kw,
                                              float* __restrict__ mags_b)
{
    const int blk = blockIdx.x;  // b*8+kv
    const __bf16* base = kw + (size_t)blk * (SEQ * HD);
    const int tid = threadIdx.x;

    float s = 0.f;
    for (int i = tid * 8; i < SEQ * HD; i += 256 * 8) {
        bf16x8 vv = *(const bf16x8*)&base[i];
#pragma unroll
        for (int j = 0; j < 8; ++j) { float f = (float)vv[j]; s += f * f; }
    }
#pragma unroll
    for (int off = 1; off < 64; off <<= 1) s += __shfl_xor(s, off, 64);

    __shared__ float red[4];
    if ((tid & 63) == 0) red[tid >> 6] = s;
    __syncthreads();
    if (tid == 0) mags_b[blk] = sqrtf(red[0] + red[1] + red[2] + red[3]);
}

// ---------------------------------------------------------------------------
// Kernel 3: ratios + kv_id (replica of _ratios + searchsorted-right)
// ---------------------------------------------------------------------------
__global__ void ratios_kernel(const float* __restrict__ mags_b,
                              const float* __restrict__ cache,
                              int* __restrict__ kv_id)
{
    if (threadIdx.x != 0 || blockIdx.x != 0) return;
    float diff[8], sum = 0.f;
    for (int j = 0; j < 8; ++j) {
        float mag = mags_b[j] + mags_b[8 + j] + mags_b[16 + j] + mags_b[24 + j];
        diff[j] = fabsf(cache[j] - mag);
        sum += diff[j];
    }
    int r[8], s = 0;
    for (int j = 0; j < 8; ++j) {
        r[j] = (int)rintf(diff[j] / sum * 16.0f);  // round half to even (jnp.round)
        s += r[j];
    }
    while (s > 16) {  // argmax (first occurrence) -= 1
        int jm = 0;
        for (int j = 1; j < 8; ++j) if (r[j] > r[jm]) jm = j;
        r[jm]--; s--;
    }
    while (s < 16) {  // argmin (first occurrence) += 1
        int jm = 0;
        for (int j = 1; j < 8; ++j) if (r[j] < r[jm]) jm = j;
        r[jm]++; s++;
    }
    int cum[8], c = 0;
    for (int j = 0; j < 8; ++j) { c += r[j]; cum[j] = c; }
    for (int h = 0; h < 16; ++h) {
        int j = 0;
        while (j < 7 && cum[j] <= h) j++;  // searchsorted side='right'
        kv_id[h] = j;
    }
}

// ---------------------------------------------------------------------------
// Kernel 4: flash attention, FIXED-SHIFT softmax (scores bounded: |s| <= 13.5
// by Cauchy-Schwarz, exp(s-10) can't overflow; softmax shift-invariant).
// No online max, no alpha rescale, l-sum deferred to epilogue.
// V^T is staged from global [d][p] layout with vector copies.
// Block = 4 waves, 64 Q rows; grid = (P/64, B*H); 32 key-blocks of 64.
// ---------------------------------------------------------------------------
__global__ __launch_bounds__(256) void attn_kernel(
    const __bf16* __restrict__ qw, const __bf16* __restrict__ kw,
    const __bf16* __restrict__ vw, const int* __restrict__ kv_id,
    __bf16* __restrict__ attn_out)
{
    __shared__ __align__(16) __bf16 Kt[64 * 72];       // [key][d], pad 72
    __shared__ __align__(16) __bf16 VT[64 * 72];       // [d][key], pad 72
    __shared__ __align__(16) __bf16 Pl[4 * 16 * 72];   // per-wave P, [row][key]

    const int bh = blockIdx.y;           // 0..63
    const int b = bh >> 4, h = bh & 15;
    const int q0 = blockIdx.x * 64;
    const int kv = kv_id[h];

    const __bf16* Kg = kw + ((size_t)(b * NKV + kv) * SEQ) * HD;    // [p][d]
    const __bf16* Vg = vw + ((size_t)(b * NKV + kv) * HD) * SEQ;    // [d][p]
    const __bf16* Qg = qw + ((size_t)(b * NH + h) * SEQ + q0) * HD;

    const int tid  = threadIdx.x;
    const int lane = tid & 63, wv = tid >> 6;
    const int l16  = lane & 15, quad = lane >> 4;

    // Q fragments (A-layout: A[m=lane&15][k=quad*8+j])
    bf16x8 qf0 = *(const bf16x8*)&Qg[(size_t)(16 * wv + l16) * HD + quad * 8];
    bf16x8 qf1 = *(const bf16x8*)&Qg[(size_t)(16 * wv + l16) * HD + 32 + quad * 8];

    float l_acc[4] = {0.f, 0.f, 0.f, 0.f};
    floatx4 o[4] = {};

    __bf16* Pw = &Pl[wv * 16 * 72];

    for (int kb = 0; kb < 32; ++kb) {
        // stage K [key][d] (vector copy) and V^T [d][key] (vector copy)
        {
            int row = tid >> 2, c0 = (tid & 3) << 4;
            const __bf16* ks = &Kg[((size_t)kb * 64 + row) * HD + c0];
            *(bf16x8*)&Kt[row * 72 + c0]     = *(const bf16x8*)ks;
            *(bf16x8*)&Kt[row * 72 + c0 + 8] = *(const bf16x8*)(ks + 8);
            const __bf16* vs = &Vg[(size_t)row * SEQ + kb * 64 + c0];
            *(bf16x8*)&VT[row * 72 + c0]     = *(const bf16x8*)vs;
            *(bf16x8*)&VT[row * 72 + c0 + 8] = *(const bf16x8*)(vs + 8);
        }
        __syncthreads();

        // S = Q K^T  (16 q-rows x 64 keys per wave)
        floatx4 sacc[4] = {};
#pragma unroll
        for (int t = 0; t < 4; ++t) {
            bf16x8 kf0 = *(bf16x8*)&Kt[(16 * t + l16) * 72 + quad * 8];
            bf16x8 kf1 = *(bf16x8*)&Kt[(16 * t + l16) * 72 + 32 + quad * 8];
            sacc[t] = __builtin_amdgcn_mfma_f32_16x16x32_bf16(qf0, kf0, sacc[t], 0, 0, 0);
            sacc[t] = __builtin_amdgcn_mfma_f32_16x16x32_bf16(qf1, kf1, sacc[t], 0, 0, 0);
        }

        // fixed-shift exp; accumulate denominator per lane (reduced at end).
        // C-layout: row = quad*4+r, col = 16t+l16.
#pragma unroll
        for (int t = 0; t < 4; ++t) {
#pragma unroll
            for (int r = 0; r < 4; ++r) {
                float e = __expf(sacc[t][r] - 10.f);
                l_acc[r] += e;
                Pw[(quad * 4 + r) * 72 + 16 * t + l16] = (__bf16)e;
            }
        }
        // P write->read is wave-local (per-wave Pl slice); DS ops are
        // wave-ordered, so no block barrier needed here.

        // O += P V   (A = P from LDS, B = V^T from LDS)
        bf16x8 a0 = *(bf16x8*)&Pw[l16 * 72 + quad * 8];
        bf16x8 a1 = *(bf16x8*)&Pw[l16 * 72 + 32 + quad * 8];
#pragma unroll
        for (int dt = 0; dt < 4; ++dt) {
            bf16x8 b0 = *(bf16x8*)&VT[(16 * dt + l16) * 72 + quad * 8];
            bf16x8 b1 = *(bf16x8*)&VT[(16 * dt + l16) * 72 + 32 + quad * 8];
            o[dt] = __builtin_amdgcn_mfma_f32_16x16x32_bf16(a0, b0, o[dt], 0, 0, 0);
            o[dt] = __builtin_amdgcn_mfma_f32_16x16x32_bf16(a1, b1, o[dt], 0, 0, 0);
        }
        __syncthreads();   // Kt/VT consumed; safe to restage next iteration
    }

    // epilogue: reduce l across the 16-lane row group, scale, store [B][P][H][D]
#pragma unroll
    for (int r = 0; r < 4; ++r) {
#pragma unroll
        for (int off = 1; off < 16; off <<= 1)
            l_acc[r] += __shfl_xor(l_acc[r], off, 64);
        float inv = 1.f / l_acc[r];
        int p_ = q0 + 16 * wv + quad * 4 + r;
#pragma unroll
        for (int dt = 0; dt < 4; ++dt) {
            int d = 16 * dt + l16;
            attn_out[(((size_t)b * SEQ + p_) * NH + h) * HD + d] = (__bf16)(o[dt][r] * inv);
        }
    }
}

// ---------------------------------------------------------------------------
// Kernel 5: output projection  attn[8192][1024](bf16) @ Wp(f32) + bp(f32)
// -> out (float32)
// ---------------------------------------------------------------------------
__global__ __launch_bounds__(256) void proj_gemm(
    const __bf16* __restrict__ A, const float* __restrict__ Wp,
    const float* __restrict__ bp, float* __restrict__ out)
{
    __shared__ __align__(16) __bf16 As[64 * 40];
    __shared__ __align__(16) __bf16 Bs[64 * 40];

    const int m0 = blockIdx.y * 64, c0 = blockIdx.x * 64;
    const int tid = threadIdx.x, lane = tid & 63, wv = tid >> 6;
    const int l16 = lane & 15, quad = lane >> 4;

    floatx4 acc[4] = {};

    for (int k0 = 0; k0 < 1024; k0 += 32) {
        {
            int m = tid >> 2, kk = (tid & 3) << 3;
            *(bf16x8*)&As[m * 40 + kk] =
                *(const bf16x8*)&A[(size_t)(m0 + m) * 1024 + k0 + kk];
        }
        {
            int kk = tid >> 3, c = (tid & 7) << 3;
            const float* wsrc = &Wp[(size_t)(k0 + kk) * 1024 + c0 + c];
            float4 w0 = *(const float4*)wsrc;
            float4 w1 = *(const float4*)(wsrc + 4);
            Bs[(c + 0) * 40 + kk] = (__bf16)w0.x;
            Bs[(c + 1) * 40 + kk] = (__bf16)w0.y;
            Bs[(c + 2) * 40 + kk] = (__bf16)w0.z;
            Bs[(c + 3) * 40 + kk] = (__bf16)w0.w;
            Bs[(c + 4) * 40 + kk] = (__bf16)w1.x;
            Bs[(c + 5) * 40 + kk] = (__bf16)w1.y;
            Bs[(c + 6) * 40 + kk] = (__bf16)w1.z;
            Bs[(c + 7) * 40 + kk] = (__bf16)w1.w;
        }
        __syncthreads();

        bf16x8 af = *(bf16x8*)&As[(16 * wv + l16) * 40 + quad * 8];
#pragma unroll
        for (int t = 0; t < 4; ++t) {
            bf16x8 bfr = *(bf16x8*)&Bs[(16 * t + l16) * 40 + quad * 8];
            acc[t] = __builtin_amdgcn_mfma_f32_16x16x32_bf16(af, bfr, acc[t], 0, 0, 0);
        }
        __syncthreads();
    }

#pragma unroll
    for (int t = 0; t < 4; ++t) {
        int c = c0 + 16 * t + l16;
        float bias = bp[c];
#pragma unroll
        for (int r = 0; r < 4; ++r) {
            int m = m0 + 16 * wv + quad * 4 + r;
            out[(size_t)m * 1024 + c] = acc[t][r] + bias;
        }
    }
}

// ---------------------------------------------------------------------------
extern "C" void kernel_launch(void* const* d_in, const int* in_sizes, int n_in,
                              void* d_out, int out_size, void* d_ws, size_t ws_size,
                              hipStream_t stream)
{
    const float* x     = (const float*)d_in[0];
    const float* Wq    = (const float*)d_in[1];
    const float* Wk    = (const float*)d_in[2];
    const float* Wv    = (const float*)d_in[3];
    const float* Wp    = (const float*)d_in[4];
    const float* bp    = (const float*)d_in[5];
    const float* cache = (const float*)d_in[6];
    float* outp = (float*)d_out;

    __bf16* ws = (__bf16*)d_ws;
    __bf16* qw = ws;                                   // [B][H][P][D]
    __bf16* kw = qw + (size_t)BSZ * NH * SEQ * HD;     // [B][HKV][P][D]
    __bf16* vw = kw + (size_t)BSZ * NKV * SEQ * HD;    // [B][HKV][D][P]  (V^T)
    __bf16* at = vw + (size_t)BSZ * NKV * SEQ * HD;    // [B][P][H*D]
    float* mags_b = (float*)(at + (size_t)BSZ * NH * SEQ * HD);  // 32 floats
    int*   kv_id  = (int*)(mags_b + 32);                          // 16 ints

    qkv_gemm<<<dim3(32, 128), 256, 0, stream>>>(x, Wq, Wk, Wv, qw, kw, vw);
    ksumsq<<<32, 256, 0, stream>>>(kw, mags_b);
    ratios_kernel<<<1, 64, 0, stream>>>(mags_b, cache, kv_id);
    attn_kernel<<<dim3(32, 64), 256, 0, stream>>>(qw, kw, vw, kv_id, at);
    proj_gemm<<<dim3(16, 128), 256, 0, stream>>>(at, Wp, bp, outp);
}

// Round 8
// 384.703 us; speedup vs baseline: 1.6497x; 1.3386x over previous
//
#include <hip/hip_runtime.h>

typedef __bf16 bf16x8 __attribute__((ext_vector_type(8)));
typedef __bf16 bf16x4 __attribute__((ext_vector_type(4)));
typedef float floatx4 __attribute__((ext_vector_type(4)));

// Sizes (fixed): B=4, P=2048, DIM=1024, H=16, HKV=8, D=64
#define BSZ 4
#define SEQ 2048
#define DIM 1024
#define NH 16
#define NKV 8
#define HD 64

// ---------------------------------------------------------------------------
// Kernel 1: fused QKV projection, 128x128 tile (m93-style), K-step 32.
// x[8192][1024](f32) @ [Wq|Wk|Wv](f32) -> q,k (bf16 [B][H][P][D]) and
// v TRANSPOSED (bf16 [B][HKV][D][P]).  q scaled by 0.125.
// 4 waves in 2x2; each wave 64x64 = 4x4 MFMA accs; 16 MFMA per K-step/wave.
// ---------------------------------------------------------------------------
__global__ __launch_bounds__(256) void qkv_gemm(
    const float* __restrict__ x,
    const float* __restrict__ Wq, const float* __restrict__ Wk,
    const float* __restrict__ Wv,
    __bf16* __restrict__ qw, __bf16* __restrict__ kw, __bf16* __restrict__ vw)
{
    __shared__ __align__(16) __bf16 As[128 * 40];   // [m][kk], pad to 40
    __shared__ __align__(16) __bf16 Bs[128 * 40];   // [c][kk]

    const int m0 = blockIdx.y * 128;
    const int c0 = blockIdx.x * 128;

    // tile never crosses the q/k/v boundaries (1024, 1536 are multiples of 128)
    const float* W; int ldn, cb, region;
    if (c0 < 1024)      { W = Wq; ldn = 1024; cb = c0;        region = 0; }
    else if (c0 < 1536) { W = Wk; ldn = 512;  cb = c0 - 1024; region = 1; }
    else                { W = Wv; ldn = 512;  cb = c0 - 1536; region = 2; }

    const int tid  = threadIdx.x;
    const int lane = tid & 63, wv = tid >> 6;
    const int l16  = lane & 15, quad = lane >> 4;
    const int wr = (wv >> 1) * 64, wc = (wv & 1) * 64;

    // staging indices
    const int ar = tid >> 3;           // A row base 0..31
    const int ac = (tid & 7) * 4;      // A fp32 col 0..28
    const int bc = tid & 127;          // B col 0..127
    const int bh = (tid >> 7) * 16;    // B k-half offset {0,16}

    floatx4 acc[4][4] = {};

    for (int k0 = 0; k0 < 1024; k0 += 32) {
        // stage A 128x32: 4 coalesced float4 rows -> bf16x4 LDS writes
#pragma unroll
        for (int j = 0; j < 4; ++j) {
            int row = ar + j * 32;
            float4 f = *(const float4*)&x[(size_t)(m0 + row) * 1024 + k0 + ac];
            bf16x4 a;
            a[0] = (__bf16)f.x; a[1] = (__bf16)f.y;
            a[2] = (__bf16)f.z; a[3] = (__bf16)f.w;
            *(bf16x4*)&As[row * 40 + ac] = a;
        }
        // stage B 32x128 transposed: 16 lane-coalesced dword loads per thread,
        // 2 vector b128 LDS writes (replaces the 16-way scalar scatter)
        {
            float v[16];
#pragma unroll
            for (int i = 0; i < 16; ++i)
                v[i] = W[(size_t)(k0 + bh + i) * ldn + cb + bc];
            bf16x8 b0, b1;
#pragma unroll
            for (int i = 0; i < 8; ++i) { b0[i] = (__bf16)v[i]; b1[i] = (__bf16)v[8 + i]; }
            *(bf16x8*)&Bs[bc * 40 + bh]     = b0;
            *(bf16x8*)&Bs[bc * 40 + bh + 8] = b1;
        }
        __syncthreads();

        bf16x8 af[4], bf[4];
#pragma unroll
        for (int t = 0; t < 4; ++t) {
            af[t] = *(bf16x8*)&As[(wr + t * 16 + l16) * 40 + quad * 8];
            bf[t] = *(bf16x8*)&Bs[(wc + t * 16 + l16) * 40 + quad * 8];
        }
#pragma unroll
        for (int mt = 0; mt < 4; ++mt)
#pragma unroll
            for (int nt = 0; nt < 4; ++nt)
                acc[mt][nt] = __builtin_amdgcn_mfma_f32_16x16x32_bf16(
                    af[mt], bf[nt], acc[mt][nt], 0, 0, 0);
        __syncthreads();
    }

    // epilogue: C/D layout col=lane&15, row=quad*4+r; region is block-uniform
#pragma unroll
    for (int mt = 0; mt < 4; ++mt) {
#pragma unroll
        for (int nt = 0; nt < 4; ++nt) {
#pragma unroll
            for (int r = 0; r < 4; ++r) {
                int m = m0 + wr + mt * 16 + quad * 4 + r;
                int c = c0 + wc + nt * 16 + l16;
                int bb = m >> 11, p = m & 2047;
                float val = acc[mt][nt][r];
                if (region == 0) {
                    int h = c >> 6, d = c & 63;
                    qw[(((size_t)bb * NH + h) * SEQ + p) * HD + d] = (__bf16)(val * 0.125f);
                } else if (region == 1) {
                    int cc = c - 1024, hh = cc >> 6, d = cc & 63;
                    kw[(((size_t)bb * NKV + hh) * SEQ + p) * HD + d] = (__bf16)val;
                } else {
                    int cc = c - 1536, hh = cc >> 6, d = cc & 63;
                    vw[(((size_t)bb * NKV + hh) * HD + d) * SEQ + p] = (__bf16)val;
                }
            }
        }
    }
}

// ---------------------------------------------------------------------------
// Kernel 2: per-(b,kv) sqrt(sum of squares of k) -> mags_b[b*8+kv]
// ---------------------------------------------------------------------------
__global__ __launch_bounds__(256) void ksumsq(const __bf16* __restrict__ kw,
                                              float* __restrict__ mags_b)
{
    const int blk = blockIdx.x;  // b*8+kv
    const __bf16* base = kw + (size_t)blk * (SEQ * HD);
    const int tid = threadIdx.x;

    float s = 0.f;
    for (int i = tid * 8; i < SEQ * HD; i += 256 * 8) {
        bf16x8 vv = *(const bf16x8*)&base[i];
#pragma unroll
        for (int j = 0; j < 8; ++j) { float f = (float)vv[j]; s += f * f; }
    }
#pragma unroll
    for (int off = 1; off < 64; off <<= 1) s += __shfl_xor(s, off, 64);

    __shared__ float red[4];
    if ((tid & 63) == 0) red[tid >> 6] = s;
    __syncthreads();
    if (tid == 0) mags_b[blk] = sqrtf(red[0] + red[1] + red[2] + red[3]);
}

// ---------------------------------------------------------------------------
// Kernel 3: ratios + kv_id (replica of _ratios + searchsorted-right)
// ---------------------------------------------------------------------------
__global__ void ratios_kernel(const float* __restrict__ mags_b,
                              const float* __restrict__ cache,
                              int* __restrict__ kv_id)
{
    if (threadIdx.x != 0 || blockIdx.x != 0) return;
    float diff[8], sum = 0.f;
    for (int j = 0; j < 8; ++j) {
        float mag = mags_b[j] + mags_b[8 + j] + mags_b[16 + j] + mags_b[24 + j];
        diff[j] = fabsf(cache[j] - mag);
        sum += diff[j];
    }
    int r[8], s = 0;
    for (int j = 0; j < 8; ++j) {
        r[j] = (int)rintf(diff[j] / sum * 16.0f);  // round half to even (jnp.round)
        s += r[j];
    }
    while (s > 16) {  // argmax (first occurrence) -= 1
        int jm = 0;
        for (int j = 1; j < 8; ++j) if (r[j] > r[jm]) jm = j;
        r[jm]--; s--;
    }
    while (s < 16) {  // argmin (first occurrence) += 1
        int jm = 0;
        for (int j = 1; j < 8; ++j) if (r[j] < r[jm]) jm = j;
        r[jm]++; s++;
    }
    int cum[8], c = 0;
    for (int j = 0; j < 8; ++j) { c += r[j]; cum[j] = c; }
    for (int h = 0; h < 16; ++h) {
        int j = 0;
        while (j < 7 && cum[j] <= h) j++;  // searchsorted side='right'
        kv_id[h] = j;
    }
}

// ---------------------------------------------------------------------------
// Kernel 4: flash attention, fixed-shift softmax (|s|<=13.5 by Cauchy-Schwarz;
// exp(s-10) safe; softmax shift-invariant).  V^T staged with vector copies.
// Block = 4 waves, 64 Q rows; grid = (P/64, B*H); 32 key-blocks of 64.
// ---------------------------------------------------------------------------
__global__ __launch_bounds__(256) void attn_kernel(
    const __bf16* __restrict__ qw, const __bf16* __restrict__ kw,
    const __bf16* __restrict__ vw, const int* __restrict__ kv_id,
    __bf16* __restrict__ attn_out)
{
    __shared__ __align__(16) __bf16 Kt[64 * 72];       // [key][d], pad 72
    __shared__ __align__(16) __bf16 VT[64 * 72];       // [d][key], pad 72
    __shared__ __align__(16) __bf16 Pl[4 * 16 * 72];   // per-wave P, [row][key]

    const int bh = blockIdx.y;           // 0..63
    const int b = bh >> 4, h = bh & 15;
    const int q0 = blockIdx.x * 64;
    const int kv = kv_id[h];

    const __bf16* Kg = kw + ((size_t)(b * NKV + kv) * SEQ) * HD;    // [p][d]
    const __bf16* Vg = vw + ((size_t)(b * NKV + kv) * HD) * SEQ;    // [d][p]
    const __bf16* Qg = qw + ((size_t)(b * NH + h) * SEQ + q0) * HD;

    const int tid  = threadIdx.x;
    const int lane = tid & 63, wv = tid >> 6;
    const int l16  = lane & 15, quad = lane >> 4;

    bf16x8 qf0 = *(const bf16x8*)&Qg[(size_t)(16 * wv + l16) * HD + quad * 8];
    bf16x8 qf1 = *(const bf16x8*)&Qg[(size_t)(16 * wv + l16) * HD + 32 + quad * 8];

    float l_acc[4] = {0.f, 0.f, 0.f, 0.f};
    floatx4 o[4] = {};

    __bf16* Pw = &Pl[wv * 16 * 72];

    for (int kb = 0; kb < 32; ++kb) {
        {
            int row = tid >> 2, cc = (tid & 3) << 4;
            const __bf16* ks = &Kg[((size_t)kb * 64 + row) * HD + cc];
            *(bf16x8*)&Kt[row * 72 + cc]     = *(const bf16x8*)ks;
            *(bf16x8*)&Kt[row * 72 + cc + 8] = *(const bf16x8*)(ks + 8);
            const __bf16* vs = &Vg[(size_t)row * SEQ + kb * 64 + cc];
            *(bf16x8*)&VT[row * 72 + cc]     = *(const bf16x8*)vs;
            *(bf16x8*)&VT[row * 72 + cc + 8] = *(const bf16x8*)(vs + 8);
        }
        __syncthreads();

        floatx4 sacc[4] = {};
#pragma unroll
        for (int t = 0; t < 4; ++t) {
            bf16x8 kf0 = *(bf16x8*)&Kt[(16 * t + l16) * 72 + quad * 8];
            bf16x8 kf1 = *(bf16x8*)&Kt[(16 * t + l16) * 72 + 32 + quad * 8];
            sacc[t] = __builtin_amdgcn_mfma_f32_16x16x32_bf16(qf0, kf0, sacc[t], 0, 0, 0);
            sacc[t] = __builtin_amdgcn_mfma_f32_16x16x32_bf16(qf1, kf1, sacc[t], 0, 0, 0);
        }

#pragma unroll
        for (int t = 0; t < 4; ++t) {
#pragma unroll
            for (int r = 0; r < 4; ++r) {
                float e = __expf(sacc[t][r] - 10.f);
                l_acc[r] += e;
                Pw[(quad * 4 + r) * 72 + 16 * t + l16] = (__bf16)e;
            }
        }
        // P write->read is wave-local; DS ops are wave-ordered: no barrier.

        bf16x8 a0 = *(bf16x8*)&Pw[l16 * 72 + quad * 8];
        bf16x8 a1 = *(bf16x8*)&Pw[l16 * 72 + 32 + quad * 8];
#pragma unroll
        for (int dt = 0; dt < 4; ++dt) {
            bf16x8 b0 = *(bf16x8*)&VT[(16 * dt + l16) * 72 + quad * 8];
            bf16x8 b1 = *(bf16x8*)&VT[(16 * dt + l16) * 72 + 32 + quad * 8];
            o[dt] = __builtin_amdgcn_mfma_f32_16x16x32_bf16(a0, b0, o[dt], 0, 0, 0);
            o[dt] = __builtin_amdgcn_mfma_f32_16x16x32_bf16(a1, b1, o[dt], 0, 0, 0);
        }
        __syncthreads();
    }

#pragma unroll
    for (int r = 0; r < 4; ++r) {
#pragma unroll
        for (int off = 1; off < 16; off <<= 1)
            l_acc[r] += __shfl_xor(l_acc[r], off, 64);
        float inv = 1.f / l_acc[r];
        int p_ = q0 + 16 * wv + quad * 4 + r;
#pragma unroll
        for (int dt = 0; dt < 4; ++dt) {
            int d = 16 * dt + l16;
            attn_out[(((size_t)b * SEQ + p_) * NH + h) * HD + d] = (__bf16)(o[dt][r] * inv);
        }
    }
}

// ---------------------------------------------------------------------------
// Kernel 5: output projection, 128x128 tile.
// attn[8192][1024](bf16) @ Wp(f32) + bp(f32) -> out (float32)
// ---------------------------------------------------------------------------
__global__ __launch_bounds__(256) void proj_gemm(
    const __bf16* __restrict__ A, const float* __restrict__ Wp,
    const float* __restrict__ bp, float* __restrict__ out)
{
    __shared__ __align__(16) __bf16 As[128 * 40];
    __shared__ __align__(16) __bf16 Bs[128 * 40];

    const int m0 = blockIdx.y * 128, c0 = blockIdx.x * 128;
    const int tid = threadIdx.x, lane = tid & 63, wv = tid >> 6;
    const int l16 = lane & 15, quad = lane >> 4;
    const int wr = (wv >> 1) * 64, wc = (wv & 1) * 64;

    const int arow = tid >> 2;          // 0..63
    const int acol = (tid & 3) * 8;     // bf16 col {0,8,16,24}
    const int bc = tid & 127;
    const int bh = (tid >> 7) * 16;

    floatx4 acc[4][4] = {};

    for (int k0 = 0; k0 < 1024; k0 += 32) {
        // stage A 128x32 bf16: 2 coalesced b128 loads -> b128 LDS writes
#pragma unroll
        for (int j = 0; j < 2; ++j) {
            int row = arow + j * 64;
            bf16x8 av = *(const bf16x8*)&A[(size_t)(m0 + row) * 1024 + k0 + acol];
            *(bf16x8*)&As[row * 40 + acol] = av;
        }
        // stage B 32x128 fp32 transposed
        {
            float v[16];
#pragma unroll
            for (int i = 0; i < 16; ++i)
                v[i] = Wp[(size_t)(k0 + bh + i) * 1024 + c0 + bc];
            bf16x8 b0, b1;
#pragma unroll
            for (int i = 0; i < 8; ++i) { b0[i] = (__bf16)v[i]; b1[i] = (__bf16)v[8 + i]; }
            *(bf16x8*)&Bs[bc * 40 + bh]     = b0;
            *(bf16x8*)&Bs[bc * 40 + bh + 8] = b1;
        }
        __syncthreads();

        bf16x8 af[4], bf[4];
#pragma unroll
        for (int t = 0; t < 4; ++t) {
            af[t] = *(bf16x8*)&As[(wr + t * 16 + l16) * 40 + quad * 8];
            bf[t] = *(bf16x8*)&Bs[(wc + t * 16 + l16) * 40 + quad * 8];
        }
#pragma unroll
        for (int mt = 0; mt < 4; ++mt)
#pragma unroll
            for (int nt = 0; nt < 4; ++nt)
                acc[mt][nt] = __builtin_amdgcn_mfma_f32_16x16x32_bf16(
                    af[mt], bf[nt], acc[mt][nt], 0, 0, 0);
        __syncthreads();
    }

#pragma unroll
    for (int nt = 0; nt < 4; ++nt) {
        int c = c0 + wc + nt * 16 + l16;
        float bias = bp[c];
#pragma unroll
        for (int mt = 0; mt < 4; ++mt)
#pragma unroll
            for (int r = 0; r < 4; ++r) {
                int m = m0 + wr + mt * 16 + quad * 4 + r;
                out[(size_t)m * 1024 + c] = acc[mt][nt][r] + bias;
            }
    }
}

// ---------------------------------------------------------------------------
extern "C" void kernel_launch(void* const* d_in, const int* in_sizes, int n_in,
                              void* d_out, int out_size, void* d_ws, size_t ws_size,
                              hipStream_t stream)
{
    const float* x     = (const float*)d_in[0];
    const float* Wq    = (const float*)d_in[1];
    const float* Wk    = (const float*)d_in[2];
    const float* Wv    = (const float*)d_in[3];
    const float* Wp    = (const float*)d_in[4];
    const float* bp    = (const float*)d_in[5];
    const float* cache = (const float*)d_in[6];
    float* outp = (float*)d_out;

    __bf16* ws = (__bf16*)d_ws;
    __bf16* qw = ws;                                   // [B][H][P][D]
    __bf16* kw = qw + (size_t)BSZ * NH * SEQ * HD;     // [B][HKV][P][D]
    __bf16* vw = kw + (size_t)BSZ * NKV * SEQ * HD;    // [B][HKV][D][P]  (V^T)
    __bf16* at = vw + (size_t)BSZ * NKV * SEQ * HD;    // [B][P][H*D]
    float* mags_b = (float*)(at + (size_t)BSZ * NH * SEQ * HD);  // 32 floats
    int*   kv_id  = (int*)(mags_b + 32);                          // 16 ints

    qkv_gemm<<<dim3(16, 64), 256, 0, stream>>>(x, Wq, Wk, Wv, qw, kw, vw);
    ksumsq<<<32, 256, 0, stream>>>(kw, mags_b);
    ratios_kernel<<<1, 64, 0, stream>>>(mags_b, cache, kv_id);
    attn_kernel<<<dim3(32, 64), 256, 0, stream>>>(qw, kw, vw, kv_id, at);
    proj_gemm<<<dim3(8, 64), 256, 0, stream>>>(at, Wp, bp, outp);
}

// Round 9
// 373.877 us; speedup vs baseline: 1.6974x; 1.0290x over previous
//
#include <hip/hip_runtime.h>

typedef __bf16 bf16x8 __attribute__((ext_vector_type(8)));
typedef __bf16 bf16x4 __attribute__((ext_vector_type(4)));
typedef float floatx4 __attribute__((ext_vector_type(4)));

// Sizes (fixed): B=4, P=2048, DIM=1024, H=16, HKV=8, D=64
#define BSZ 4
#define SEQ 2048
#define DIM 1024
#define NH 16
#define NKV 8
#define HD 64

// ---------------------------------------------------------------------------
// Kernel 1: fused QKV projection, 128x128 tile, K-step 32.
// x[8192][1024](f32) @ [Wq|Wk|Wv](f32) -> q,k (bf16 [B][H][P][D]) and
// v TRANSPOSED (bf16 [B][HKV][D][P]).  q scaled by 0.125.
// ---------------------------------------------------------------------------
__global__ __launch_bounds__(256) void qkv_gemm(
    const float* __restrict__ x,
    const float* __restrict__ Wq, const float* __restrict__ Wk,
    const float* __restrict__ Wv,
    __bf16* __restrict__ qw, __bf16* __restrict__ kw, __bf16* __restrict__ vw)
{
    __shared__ __align__(16) __bf16 As[128 * 40];   // [m][kk], pad to 40
    __shared__ __align__(16) __bf16 Bs[128 * 40];   // [c][kk]

    const int m0 = blockIdx.y * 128;
    const int c0 = blockIdx.x * 128;

    const float* W; int ldn, cb, region;
    if (c0 < 1024)      { W = Wq; ldn = 1024; cb = c0;        region = 0; }
    else if (c0 < 1536) { W = Wk; ldn = 512;  cb = c0 - 1024; region = 1; }
    else                { W = Wv; ldn = 512;  cb = c0 - 1536; region = 2; }

    const int tid  = threadIdx.x;
    const int lane = tid & 63, wv = tid >> 6;
    const int l16  = lane & 15, quad = lane >> 4;
    const int wr = (wv >> 1) * 64, wc = (wv & 1) * 64;

    const int ar = tid >> 3;           // A row base 0..31
    const int ac = (tid & 7) * 4;      // A fp32 col
    const int bc = tid & 127;          // B col 0..127
    const int bh = (tid >> 7) * 16;    // B k-half {0,16}

    floatx4 acc[4][4] = {};

    for (int k0 = 0; k0 < 1024; k0 += 32) {
#pragma unroll
        for (int j = 0; j < 4; ++j) {
            int row = ar + j * 32;
            float4 f = *(const float4*)&x[(size_t)(m0 + row) * 1024 + k0 + ac];
            bf16x4 a;
            a[0] = (__bf16)f.x; a[1] = (__bf16)f.y;
            a[2] = (__bf16)f.z; a[3] = (__bf16)f.w;
            *(bf16x4*)&As[row * 40 + ac] = a;
        }
        {
            float v[16];
#pragma unroll
            for (int i = 0; i < 16; ++i)
                v[i] = W[(size_t)(k0 + bh + i) * ldn + cb + bc];
            bf16x8 b0, b1;
#pragma unroll
            for (int i = 0; i < 8; ++i) { b0[i] = (__bf16)v[i]; b1[i] = (__bf16)v[8 + i]; }
            *(bf16x8*)&Bs[bc * 40 + bh]     = b0;
            *(bf16x8*)&Bs[bc * 40 + bh + 8] = b1;
        }
        __syncthreads();

        bf16x8 af[4], bf[4];
#pragma unroll
        for (int t = 0; t < 4; ++t) {
            af[t] = *(bf16x8*)&As[(wr + t * 16 + l16) * 40 + quad * 8];
            bf[t] = *(bf16x8*)&Bs[(wc + t * 16 + l16) * 40 + quad * 8];
        }
#pragma unroll
        for (int mt = 0; mt < 4; ++mt)
#pragma unroll
            for (int nt = 0; nt < 4; ++nt)
                acc[mt][nt] = __builtin_amdgcn_mfma_f32_16x16x32_bf16(
                    af[mt], bf[nt], acc[mt][nt], 0, 0, 0);
        __syncthreads();
    }

#pragma unroll
    for (int mt = 0; mt < 4; ++mt) {
#pragma unroll
        for (int nt = 0; nt < 4; ++nt) {
#pragma unroll
            for (int r = 0; r < 4; ++r) {
                int m = m0 + wr + mt * 16 + quad * 4 + r;
                int c = c0 + wc + nt * 16 + l16;
                int bb = m >> 11, p = m & 2047;
                float val = acc[mt][nt][r];
                if (region == 0) {
                    int h = c >> 6, d = c & 63;
                    qw[(((size_t)bb * NH + h) * SEQ + p) * HD + d] = (__bf16)(val * 0.125f);
                } else if (region == 1) {
                    int cc = c - 1024, hh = cc >> 6, d = cc & 63;
                    kw[(((size_t)bb * NKV + hh) * SEQ + p) * HD + d] = (__bf16)val;
                } else {
                    int cc = c - 1536, hh = cc >> 6, d = cc & 63;
                    vw[(((size_t)bb * NKV + hh) * HD + d) * SEQ + p] = (__bf16)val;
                }
            }
        }
    }
}

// ---------------------------------------------------------------------------
// Kernel 2: per-(b,kv) sqrt(sum of squares of k) -> mags_b[b*8+kv]
// ---------------------------------------------------------------------------
__global__ __launch_bounds__(256) void ksumsq(const __bf16* __restrict__ kw,
                                              float* __restrict__ mags_b)
{
    const int blk = blockIdx.x;  // b*8+kv
    const __bf16* base = kw + (size_t)blk * (SEQ * HD);
    const int tid = threadIdx.x;

    float s = 0.f;
    for (int i = tid * 8; i < SEQ * HD; i += 256 * 8) {
        bf16x8 vv = *(const bf16x8*)&base[i];
#pragma unroll
        for (int j = 0; j < 8; ++j) { float f = (float)vv[j]; s += f * f; }
    }
#pragma unroll
    for (int off = 1; off < 64; off <<= 1) s += __shfl_xor(s, off, 64);

    __shared__ float red[4];
    if ((tid & 63) == 0) red[tid >> 6] = s;
    __syncthreads();
    if (tid == 0) mags_b[blk] = sqrtf(red[0] + red[1] + red[2] + red[3]);
}

// ---------------------------------------------------------------------------
// Kernel 3: ratios + kv_id (replica of _ratios + searchsorted-right)
// ---------------------------------------------------------------------------
__global__ void ratios_kernel(const float* __restrict__ mags_b,
                              const float* __restrict__ cache,
                              int* __restrict__ kv_id)
{
    if (threadIdx.x != 0 || blockIdx.x != 0) return;
    float diff[8], sum = 0.f;
    for (int j = 0; j < 8; ++j) {
        float mag = mags_b[j] + mags_b[8 + j] + mags_b[16 + j] + mags_b[24 + j];
        diff[j] = fabsf(cache[j] - mag);
        sum += diff[j];
    }
    int r[8], s = 0;
    for (int j = 0; j < 8; ++j) {
        r[j] = (int)rintf(diff[j] / sum * 16.0f);  // round half to even (jnp.round)
        s += r[j];
    }
    while (s > 16) {
        int jm = 0;
        for (int j = 1; j < 8; ++j) if (r[j] > r[jm]) jm = j;
        r[jm]--; s--;
    }
    while (s < 16) {
        int jm = 0;
        for (int j = 1; j < 8; ++j) if (r[j] < r[jm]) jm = j;
        r[jm]++; s++;
    }
    int cum[8], c = 0;
    for (int j = 0; j < 8; ++j) { c += r[j]; cum[j] = c; }
    for (int h = 0; h < 16; ++h) {
        int j = 0;
        while (j < 7 && cum[j] <= h) j++;  // searchsorted side='right'
        kv_id[h] = j;
    }
}

// ---------------------------------------------------------------------------
// Kernel 4: flash attention, fixed-shift softmax, S computed TRANSPOSED:
// S^T = mfma(K_frag, Q_frag) -> C-layout row=key(quad*4+r), col=qrow(l16).
// Lane's 4 values are consecutive keys of one q-row -> P store is one
// ds_write_b64 per key-tile (was 16 scalar b16 scatters), and the softmax
// denominator is a single per-lane accumulator (all values share qrow=l16).
// Block = 4 waves, 64 Q rows; grid = (P/64, B*H); 32 key-blocks of 64.
// ---------------------------------------------------------------------------
__global__ __launch_bounds__(256) void attn_kernel(
    const __bf16* __restrict__ qw, const __bf16* __restrict__ kw,
    const __bf16* __restrict__ vw, const int* __restrict__ kv_id,
    __bf16* __restrict__ attn_out)
{
    __shared__ __align__(16) __bf16 Kt[64 * 72];       // [key][d], pad 72
    __shared__ __align__(16) __bf16 VT[64 * 72];       // [d][key], pad 72
    __shared__ __align__(16) __bf16 Pl[4 * 16 * 72];   // per-wave P, [qrow][key]

    const int bh = blockIdx.y;           // 0..63
    const int b = bh >> 4, h = bh & 15;
    const int q0 = blockIdx.x * 64;
    const int kv = kv_id[h];

    const __bf16* Kg = kw + ((size_t)(b * NKV + kv) * SEQ) * HD;    // [p][d]
    const __bf16* Vg = vw + ((size_t)(b * NKV + kv) * HD) * SEQ;    // [d][p]
    const __bf16* Qg = qw + ((size_t)(b * NH + h) * SEQ + q0) * HD;

    const int tid  = threadIdx.x;
    const int lane = tid & 63, wv = tid >> 6;
    const int l16  = lane & 15, quad = lane >> 4;

    // Q fragment: Q[qrow=l16][k=quad*8+j] — valid as the B operand of S^T
    bf16x8 qf0 = *(const bf16x8*)&Qg[(size_t)(16 * wv + l16) * HD + quad * 8];
    bf16x8 qf1 = *(const bf16x8*)&Qg[(size_t)(16 * wv + l16) * HD + 32 + quad * 8];

    float l_acc = 0.f;     // denominator for qrow = 16*wv + l16 (partial: this quad's keys)
    floatx4 o[4] = {};

    __bf16* Pw = &Pl[wv * 16 * 72];

    for (int kb = 0; kb < 32; ++kb) {
        // stage K [key][d] and V^T [d][key] with b128 copies
        {
            int row = tid >> 2, cc = (tid & 3) << 4;
            const __bf16* ks = &Kg[((size_t)kb * 64 + row) * HD + cc];
            *(bf16x8*)&Kt[row * 72 + cc]     = *(const bf16x8*)ks;
            *(bf16x8*)&Kt[row * 72 + cc + 8] = *(const bf16x8*)(ks + 8);
            const __bf16* vs = &Vg[(size_t)row * SEQ + kb * 64 + cc];
            *(bf16x8*)&VT[row * 72 + cc]     = *(const bf16x8*)vs;
            *(bf16x8*)&VT[row * 72 + cc + 8] = *(const bf16x8*)(vs + 8);
        }
        __syncthreads();

        // S^T = K Q^T: A = K_frag (m=key), B = Q_frag (n=qrow)
        floatx4 sacc[4] = {};
#pragma unroll
        for (int t = 0; t < 4; ++t) {
            bf16x8 kf0 = *(bf16x8*)&Kt[(16 * t + l16) * 72 + quad * 8];
            bf16x8 kf1 = *(bf16x8*)&Kt[(16 * t + l16) * 72 + 32 + quad * 8];
            sacc[t] = __builtin_amdgcn_mfma_f32_16x16x32_bf16(kf0, qf0, sacc[t], 0, 0, 0);
            sacc[t] = __builtin_amdgcn_mfma_f32_16x16x32_bf16(kf1, qf1, sacc[t], 0, 0, 0);
        }

        // fixed-shift exp (|s|<=13.5 by Cauchy-Schwarz; shift-invariant).
        // S^T C-layout: key = 16t + quad*4 + r, qrow = l16 -> b64 P stores.
#pragma unroll
        for (int t = 0; t < 4; ++t) {
            bf16x4 pv;
#pragma unroll
            for (int r = 0; r < 4; ++r) {
                float e = __expf(sacc[t][r] - 10.f);
                l_acc += e;
                pv[r] = (__bf16)e;
            }
            *(bf16x4*)&Pw[l16 * 72 + 16 * t + quad * 4] = pv;
        }
        // P write->read is wave-local; DS ops are wave-ordered: no barrier.

        // O += P V  (A = P[qrow][key] from LDS, B = V^T[d][key] from LDS)
        bf16x8 a0 = *(bf16x8*)&Pw[l16 * 72 + quad * 8];
        bf16x8 a1 = *(bf16x8*)&Pw[l16 * 72 + 32 + quad * 8];
#pragma unroll
        for (int dt = 0; dt < 4; ++dt) {
            bf16x8 b0 = *(bf16x8*)&VT[(16 * dt + l16) * 72 + quad * 8];
            bf16x8 b1 = *(bf16x8*)&VT[(16 * dt + l16) * 72 + 32 + quad * 8];
            o[dt] = __builtin_amdgcn_mfma_f32_16x16x32_bf16(a0, b0, o[dt], 0, 0, 0);
            o[dt] = __builtin_amdgcn_mfma_f32_16x16x32_bf16(a1, b1, o[dt], 0, 0, 0);
        }
        __syncthreads();
    }

    // epilogue: finish denominator (sum across quads), fetch per-row inverse,
    // scale, store [B][P][H][D]
    l_acc += __shfl_xor(l_acc, 16, 64);
    l_acc += __shfl_xor(l_acc, 32, 64);   // lane now holds denom for qrow=16wv+l16
#pragma unroll
    for (int r = 0; r < 4; ++r) {
        float lr = __shfl(l_acc, quad * 4 + r, 64);   // denom of qrow quad*4+r
        float inv = 1.f / lr;
        int p_ = q0 + 16 * wv + quad * 4 + r;
#pragma unroll
        for (int dt = 0; dt < 4; ++dt) {
            int d = 16 * dt + l16;
            attn_out[(((size_t)b * SEQ + p_) * NH + h) * HD + d] = (__bf16)(o[dt][r] * inv);
        }
    }
}

// ---------------------------------------------------------------------------
// Kernel 5: output projection, 128x128 tile.
// attn[8192][1024](bf16) @ Wp(f32) + bp(f32) -> out (float32)
// ---------------------------------------------------------------------------
__global__ __launch_bounds__(256) void proj_gemm(
    const __bf16* __restrict__ A, const float* __restrict__ Wp,
    const float* __restrict__ bp, float* __restrict__ out)
{
    __shared__ __align__(16) __bf16 As[128 * 40];
    __shared__ __align__(16) __bf16 Bs[128 * 40];

    const int m0 = blockIdx.y * 128, c0 = blockIdx.x * 128;
    const int tid = threadIdx.x, lane = tid & 63, wv = tid >> 6;
    const int l16 = lane & 15, quad = lane >> 4;
    const int wr = (wv >> 1) * 64, wc = (wv & 1) * 64;

    const int arow = tid >> 2;
    const int acol = (tid & 3) * 8;
    const int bc = tid & 127;
    const int bh = (tid >> 7) * 16;

    floatx4 acc[4][4] = {};

    for (int k0 = 0; k0 < 1024; k0 += 32) {
#pragma unroll
        for (int j = 0; j < 2; ++j) {
            int row = arow + j * 64;
            bf16x8 av = *(const bf16x8*)&A[(size_t)(m0 + row) * 1024 + k0 + acol];
            *(bf16x8*)&As[row * 40 + acol] = av;
        }
        {
            float v[16];
#pragma unroll
            for (int i = 0; i < 16; ++i)
                v[i] = Wp[(size_t)(k0 + bh + i) * 1024 + c0 + bc];
            bf16x8 b0, b1;
#pragma unroll
            for (int i = 0; i < 8; ++i) { b0[i] = (__bf16)v[i]; b1[i] = (__bf16)v[8 + i]; }
            *(bf16x8*)&Bs[bc * 40 + bh]     = b0;
            *(bf16x8*)&Bs[bc * 40 + bh + 8] = b1;
        }
        __syncthreads();

        bf16x8 af[4], bf[4];
#pragma unroll
        for (int t = 0; t < 4; ++t) {
            af[t] = *(bf16x8*)&As[(wr + t * 16 + l16) * 40 + quad * 8];
            bf[t] = *(bf16x8*)&Bs[(wc + t * 16 + l16) * 40 + quad * 8];
        }
#pragma unroll
        for (int mt = 0; mt < 4; ++mt)
#pragma unroll
            for (int nt = 0; nt < 4; ++nt)
                acc[mt][nt] = __builtin_amdgcn_mfma_f32_16x16x32_bf16(
                    af[mt], bf[nt], acc[mt][nt], 0, 0, 0);
        __syncthreads();
    }

#pragma unroll
    for (int nt = 0; nt < 4; ++nt) {
        int c = c0 + wc + nt * 16 + l16;
        float bias = bp[c];
#pragma unroll
        for (int mt = 0; mt < 4; ++mt)
#pragma unroll
            for (int r = 0; r < 4; ++r) {
                int m = m0 + wr + mt * 16 + quad * 4 + r;
                out[(size_t)m * 1024 + c] = acc[mt][nt][r] + bias;
            }
    }
}

// ---------------------------------------------------------------------------
extern "C" void kernel_launch(void* const* d_in, const int* in_sizes, int n_in,
                              void* d_out, int out_size, void* d_ws, size_t ws_size,
                              hipStream_t stream)
{
    const float* x     = (const float*)d_in[0];
    const float* Wq    = (const float*)d_in[1];
    const float* Wk    = (const float*)d_in[2];
    const float* Wv    = (const float*)d_in[3];
    const float* Wp    = (const float*)d_in[4];
    const float* bp    = (const float*)d_in[5];
    const float* cache = (const float*)d_in[6];
    float* outp = (float*)d_out;

    __bf16* ws = (__bf16*)d_ws;
    __bf16* qw = ws;                                   // [B][H][P][D]
    __bf16* kw = qw + (size_t)BSZ * NH * SEQ * HD;     // [B][HKV][P][D]
    __bf16* vw = kw + (size_t)BSZ * NKV * SEQ * HD;    // [B][HKV][D][P]  (V^T)
    __bf16* at = vw + (size_t)BSZ * NKV * SEQ * HD;    // [B][P][H*D]
    float* mags_b = (float*)(at + (size_t)BSZ * NH * SEQ * HD);  // 32 floats
    int*   kv_id  = (int*)(mags_b + 32);                          // 16 ints

    qkv_gemm<<<dim3(16, 64), 256, 0, stream>>>(x, Wq, Wk, Wv, qw, kw, vw);
    ksumsq<<<32, 256, 0, stream>>>(kw, mags_b);
    ratios_kernel<<<1, 64, 0, stream>>>(mags_b, cache, kv_id);
    attn_kernel<<<dim3(32, 64), 256, 0, stream>>>(qw, kw, vw, kv_id, at);
    proj_gemm<<<dim3(8, 64), 256, 0, stream>>>(at, Wp, bp, outp);
}

// Round 10
// 369.917 us; speedup vs baseline: 1.7156x; 1.0107x over previous
//
#include <hip/hip_runtime.h>

typedef __bf16 bf16x8 __attribute__((ext_vector_type(8)));
typedef __bf16 bf16x4 __attribute__((ext_vector_type(4)));
typedef float floatx4 __attribute__((ext_vector_type(4)));

// Sizes (fixed): B=4, P=2048, DIM=1024, H=16, HKV=8, D=64
#define BSZ 4
#define SEQ 2048
#define DIM 1024
#define NH 16
#define NKV 8
#define HD 64

// ---------------------------------------------------------------------------
// Kernel 1: fused QKV projection, 128x128 tile, K-step 32.
// x[8192][1024](f32) @ [Wq|Wk|Wv](f32) -> q,k (bf16 [B][H][P][D]) and
// v TRANSPOSED (bf16 [B][HKV][D][P]).  q scaled by 0.125.
// ---------------------------------------------------------------------------
__global__ __launch_bounds__(256) void qkv_gemm(
    const float* __restrict__ x,
    const float* __restrict__ Wq, const float* __restrict__ Wk,
    const float* __restrict__ Wv,
    __bf16* __restrict__ qw, __bf16* __restrict__ kw, __bf16* __restrict__ vw)
{
    __shared__ __align__(16) __bf16 As[128 * 40];   // [m][kk], pad to 40
    __shared__ __align__(16) __bf16 Bs[128 * 40];   // [c][kk]

    const int m0 = blockIdx.y * 128;
    const int c0 = blockIdx.x * 128;

    const float* W; int ldn, cb, region;
    if (c0 < 1024)      { W = Wq; ldn = 1024; cb = c0;        region = 0; }
    else if (c0 < 1536) { W = Wk; ldn = 512;  cb = c0 - 1024; region = 1; }
    else                { W = Wv; ldn = 512;  cb = c0 - 1536; region = 2; }

    const int tid  = threadIdx.x;
    const int lane = tid & 63, wv = tid >> 6;
    const int l16  = lane & 15, quad = lane >> 4;
    const int wr = (wv >> 1) * 64, wc = (wv & 1) * 64;

    const int ar = tid >> 3;           // A row base 0..31
    const int ac = (tid & 7) * 4;      // A fp32 col
    const int bc = tid & 127;          // B col 0..127
    const int bh = (tid >> 7) * 16;    // B k-half {0,16}

    floatx4 acc[4][4] = {};

    for (int k0 = 0; k0 < 1024; k0 += 32) {
#pragma unroll
        for (int j = 0; j < 4; ++j) {
            int row = ar + j * 32;
            float4 f = *(const float4*)&x[(size_t)(m0 + row) * 1024 + k0 + ac];
            bf16x4 a;
            a[0] = (__bf16)f.x; a[1] = (__bf16)f.y;
            a[2] = (__bf16)f.z; a[3] = (__bf16)f.w;
            *(bf16x4*)&As[row * 40 + ac] = a;
        }
        {
            float v[16];
#pragma unroll
            for (int i = 0; i < 16; ++i)
                v[i] = W[(size_t)(k0 + bh + i) * ldn + cb + bc];
            bf16x8 b0, b1;
#pragma unroll
            for (int i = 0; i < 8; ++i) { b0[i] = (__bf16)v[i]; b1[i] = (__bf16)v[8 + i]; }
            *(bf16x8*)&Bs[bc * 40 + bh]     = b0;
            *(bf16x8*)&Bs[bc * 40 + bh + 8] = b1;
        }
        __syncthreads();

        bf16x8 af[4], bf[4];
#pragma unroll
        for (int t = 0; t < 4; ++t) {
            af[t] = *(bf16x8*)&As[(wr + t * 16 + l16) * 40 + quad * 8];
            bf[t] = *(bf16x8*)&Bs[(wc + t * 16 + l16) * 40 + quad * 8];
        }
#pragma unroll
        for (int mt = 0; mt < 4; ++mt)
#pragma unroll
            for (int nt = 0; nt < 4; ++nt)
                acc[mt][nt] = __builtin_amdgcn_mfma_f32_16x16x32_bf16(
                    af[mt], bf[nt], acc[mt][nt], 0, 0, 0);
        __syncthreads();
    }

#pragma unroll
    for (int mt = 0; mt < 4; ++mt) {
#pragma unroll
        for (int nt = 0; nt < 4; ++nt) {
#pragma unroll
            for (int r = 0; r < 4; ++r) {
                int m = m0 + wr + mt * 16 + quad * 4 + r;
                int c = c0 + wc + nt * 16 + l16;
                int bb = m >> 11, p = m & 2047;
                float val = acc[mt][nt][r];
                if (region == 0) {
                    int h = c >> 6, d = c & 63;
                    qw[(((size_t)bb * NH + h) * SEQ + p) * HD + d] = (__bf16)(val * 0.125f);
                } else if (region == 1) {
                    int cc = c - 1024, hh = cc >> 6, d = cc & 63;
                    kw[(((size_t)bb * NKV + hh) * SEQ + p) * HD + d] = (__bf16)val;
                } else {
                    int cc = c - 1536, hh = cc >> 6, d = cc & 63;
                    vw[(((size_t)bb * NKV + hh) * HD + d) * SEQ + p] = (__bf16)val;
                }
            }
        }
    }
}

// ---------------------------------------------------------------------------
// Kernel 2: per-(b,kv) sqrt(sum of squares of k) -> mags_b[b*8+kv]
// ---------------------------------------------------------------------------
__global__ __launch_bounds__(256) void ksumsq(const __bf16* __restrict__ kw,
                                              float* __restrict__ mags_b)
{
    const int blk = blockIdx.x;  // b*8+kv
    const __bf16* base = kw + (size_t)blk * (SEQ * HD);
    const int tid = threadIdx.x;

    float s = 0.f;
    for (int i = tid * 8; i < SEQ * HD; i += 256 * 8) {
        bf16x8 vv = *(const bf16x8*)&base[i];
#pragma unroll
        for (int j = 0; j < 8; ++j) { float f = (float)vv[j]; s += f * f; }
    }
#pragma unroll
    for (int off = 1; off < 64; off <<= 1) s += __shfl_xor(s, off, 64);

    __shared__ float red[4];
    if ((tid & 63) == 0) red[tid >> 6] = s;
    __syncthreads();
    if (tid == 0) mags_b[blk] = sqrtf(red[0] + red[1] + red[2] + red[3]);
}

// ---------------------------------------------------------------------------
// Kernel 3: ratios + kv_id (replica of _ratios + searchsorted-right)
// ---------------------------------------------------------------------------
__global__ void ratios_kernel(const float* __restrict__ mags_b,
                              const float* __restrict__ cache,
                              int* __restrict__ kv_id)
{
    if (threadIdx.x != 0 || blockIdx.x != 0) return;
    float diff[8], sum = 0.f;
    for (int j = 0; j < 8; ++j) {
        float mag = mags_b[j] + mags_b[8 + j] + mags_b[16 + j] + mags_b[24 + j];
        diff[j] = fabsf(cache[j] - mag);
        sum += diff[j];
    }
    int r[8], s = 0;
    for (int j = 0; j < 8; ++j) {
        r[j] = (int)rintf(diff[j] / sum * 16.0f);  // round half to even (jnp.round)
        s += r[j];
    }
    while (s > 16) {
        int jm = 0;
        for (int j = 1; j < 8; ++j) if (r[j] > r[jm]) jm = j;
        r[jm]--; s--;
    }
    while (s < 16) {
        int jm = 0;
        for (int j = 1; j < 8; ++j) if (r[j] < r[jm]) jm = j;
        r[jm]++; s++;
    }
    int cum[8], c = 0;
    for (int j = 0; j < 8; ++j) { c += r[j]; cum[j] = c; }
    for (int h = 0; h < 16; ++h) {
        int j = 0;
        while (j < 7 && cum[j] <= h) j++;  // searchsorted side='right'
        kv_id[h] = j;
    }
}

// ---------------------------------------------------------------------------
// Kernel 4: flash attention, fixed-shift softmax, S^T = mfma(K, Q).
// ILP version: each wave owns 32 q-rows (2 independent fragment sets),
// block covers 128 q-rows; grid (P/128, B*H) = 1024 blocks = 4/CU.
// K-fragments hoisted to registers, shared by both sets.
// ---------------------------------------------------------------------------
__global__ __launch_bounds__(256) void attn_kernel(
    const __bf16* __restrict__ qw, const __bf16* __restrict__ kw,
    const __bf16* __restrict__ vw, const int* __restrict__ kv_id,
    __bf16* __restrict__ attn_out)
{
    __shared__ __align__(16) __bf16 Kt[64 * 72];       // [key][d], pad 72
    __shared__ __align__(16) __bf16 VT[64 * 72];       // [d][key], pad 72
    __shared__ __align__(16) __bf16 Pl[4 * 32 * 72];   // per-wave P, [qrow][key]

    const int bh = blockIdx.y;           // 0..63
    const int b = bh >> 4, h = bh & 15;
    const int q0 = blockIdx.x * 128;
    const int kv = kv_id[h];

    const __bf16* Kg = kw + ((size_t)(b * NKV + kv) * SEQ) * HD;    // [p][d]
    const __bf16* Vg = vw + ((size_t)(b * NKV + kv) * HD) * SEQ;    // [d][p]
    const __bf16* Qg = qw + ((size_t)(b * NH + h) * SEQ + q0) * HD;

    const int tid  = threadIdx.x;
    const int lane = tid & 63, wv = tid >> 6;
    const int l16  = lane & 15, quad = lane >> 4;

    // Two independent Q fragment sets: qrow = 32*wv + 16*s + l16
    bf16x8 qf[2][2];
#pragma unroll
    for (int s = 0; s < 2; ++s) {
        const __bf16* qp = &Qg[(size_t)(32 * wv + 16 * s + l16) * HD];
        qf[s][0] = *(const bf16x8*)&qp[quad * 8];
        qf[s][1] = *(const bf16x8*)&qp[32 + quad * 8];
    }

    float l_acc[2] = {0.f, 0.f};
    floatx4 o[2][4] = {};

    __bf16* Pw = &Pl[wv * 32 * 72];

    for (int kb = 0; kb < 32; ++kb) {
        // stage K [key][d] and V^T [d][key] with b128 copies
        {
            int row = tid >> 2, cc = (tid & 3) << 4;
            const __bf16* ks = &Kg[((size_t)kb * 64 + row) * HD + cc];
            *(bf16x8*)&Kt[row * 72 + cc]     = *(const bf16x8*)ks;
            *(bf16x8*)&Kt[row * 72 + cc + 8] = *(const bf16x8*)(ks + 8);
            const __bf16* vs = &Vg[(size_t)row * SEQ + kb * 64 + cc];
            *(bf16x8*)&VT[row * 72 + cc]     = *(const bf16x8*)vs;
            *(bf16x8*)&VT[row * 72 + cc + 8] = *(const bf16x8*)(vs + 8);
        }
        __syncthreads();

        // K fragments once, reused by both q-sets
        bf16x8 kf[4][2];
#pragma unroll
        for (int t = 0; t < 4; ++t) {
            kf[t][0] = *(bf16x8*)&Kt[(16 * t + l16) * 72 + quad * 8];
            kf[t][1] = *(bf16x8*)&Kt[(16 * t + l16) * 72 + 32 + quad * 8];
        }

        // S^T = K Q^T per set; fixed-shift exp; b64 P stores
#pragma unroll
        for (int s = 0; s < 2; ++s) {
            floatx4 sacc[4] = {};
#pragma unroll
            for (int t = 0; t < 4; ++t) {
                sacc[t] = __builtin_amdgcn_mfma_f32_16x16x32_bf16(kf[t][0], qf[s][0], sacc[t], 0, 0, 0);
                sacc[t] = __builtin_amdgcn_mfma_f32_16x16x32_bf16(kf[t][1], qf[s][1], sacc[t], 0, 0, 0);
            }
#pragma unroll
            for (int t = 0; t < 4; ++t) {
                bf16x4 pv;
#pragma unroll
                for (int r = 0; r < 4; ++r) {
                    float e = __expf(sacc[t][r] - 10.f);
                    l_acc[s] += e;
                    pv[r] = (__bf16)e;
                }
                *(bf16x4*)&Pw[(16 * s + l16) * 72 + 16 * t + quad * 4] = pv;
            }
        }
        // P write->read is wave-local; DS ops are wave-ordered: no barrier.

        // O += P V per set (V^T fragments shared via LDS reads)
#pragma unroll
        for (int s = 0; s < 2; ++s) {
            bf16x8 a0 = *(bf16x8*)&Pw[(16 * s + l16) * 72 + quad * 8];
            bf16x8 a1 = *(bf16x8*)&Pw[(16 * s + l16) * 72 + 32 + quad * 8];
#pragma unroll
            for (int dt = 0; dt < 4; ++dt) {
                bf16x8 b0 = *(bf16x8*)&VT[(16 * dt + l16) * 72 + quad * 8];
                bf16x8 b1 = *(bf16x8*)&VT[(16 * dt + l16) * 72 + 32 + quad * 8];
                o[s][dt] = __builtin_amdgcn_mfma_f32_16x16x32_bf16(a0, b0, o[s][dt], 0, 0, 0);
                o[s][dt] = __builtin_amdgcn_mfma_f32_16x16x32_bf16(a1, b1, o[s][dt], 0, 0, 0);
            }
        }
        __syncthreads();
    }

    // epilogue per set: finish denominator, scale, store [B][P][H][D]
#pragma unroll
    for (int s = 0; s < 2; ++s) {
        float l = l_acc[s];
        l += __shfl_xor(l, 16, 64);
        l += __shfl_xor(l, 32, 64);   // lane holds denom for qrow 32wv+16s+l16
#pragma unroll
        for (int r = 0; r < 4; ++r) {
            float lr = __shfl(l, quad * 4 + r, 64);   // denom of row-offset quad*4+r
            float inv = 1.f / lr;
            int p_ = q0 + 32 * wv + 16 * s + quad * 4 + r;
#pragma unroll
            for (int dt = 0; dt < 4; ++dt) {
                int d = 16 * dt + l16;
                attn_out[(((size_t)b * SEQ + p_) * NH + h) * HD + d] = (__bf16)(o[s][dt][r] * inv);
            }
        }
    }
}

// ---------------------------------------------------------------------------
// Kernel 5: output projection, 128x128 tile.
// attn[8192][1024](bf16) @ Wp(f32) + bp(f32) -> out (float32)
// ---------------------------------------------------------------------------
__global__ __launch_bounds__(256) void proj_gemm(
    const __bf16* __restrict__ A, const float* __restrict__ Wp,
    const float* __restrict__ bp, float* __restrict__ out)
{
    __shared__ __align__(16) __bf16 As[128 * 40];
    __shared__ __align__(16) __bf16 Bs[128 * 40];

    const int m0 = blockIdx.y * 128, c0 = blockIdx.x * 128;
    const int tid = threadIdx.x, lane = tid & 63, wv = tid >> 6;
    const int l16 = lane & 15, quad = lane >> 4;
    const int wr = (wv >> 1) * 64, wc = (wv & 1) * 64;

    const int arow = tid >> 2;
    const int acol = (tid & 3) * 8;
    const int bc = tid & 127;
    const int bh = (tid >> 7) * 16;

    floatx4 acc[4][4] = {};

    for (int k0 = 0; k0 < 1024; k0 += 32) {
#pragma unroll
        for (int j = 0; j < 2; ++j) {
            int row = arow + j * 64;
            bf16x8 av = *(const bf16x8*)&A[(size_t)(m0 + row) * 1024 + k0 + acol];
            *(bf16x8*)&As[row * 40 + acol] = av;
        }
        {
            float v[16];
#pragma unroll
            for (int i = 0; i < 16; ++i)
                v[i] = Wp[(size_t)(k0 + bh + i) * 1024 + c0 + bc];
            bf16x8 b0, b1;
#pragma unroll
            for (int i = 0; i < 8; ++i) { b0[i] = (__bf16)v[i]; b1[i] = (__bf16)v[8 + i]; }
            *(bf16x8*)&Bs[bc * 40 + bh]     = b0;
            *(bf16x8*)&Bs[bc * 40 + bh + 8] = b1;
        }
        __syncthreads();

        bf16x8 af[4], bf[4];
#pragma unroll
        for (int t = 0; t < 4; ++t) {
            af[t] = *(bf16x8*)&As[(wr + t * 16 + l16) * 40 + quad * 8];
            bf[t] = *(bf16x8*)&Bs[(wc + t * 16 + l16) * 40 + quad * 8];
        }
#pragma unroll
        for (int mt = 0; mt < 4; ++mt)
#pragma unroll
            for (int nt = 0; nt < 4; ++nt)
                acc[mt][nt] = __builtin_amdgcn_mfma_f32_16x16x32_bf16(
                    af[mt], bf[nt], acc[mt][nt], 0, 0, 0);
        __syncthreads();
    }

#pragma unroll
    for (int nt = 0; nt < 4; ++nt) {
        int c = c0 + wc + nt * 16 + l16;
        float bias = bp[c];
#pragma unroll
        for (int mt = 0; mt < 4; ++mt)
#pragma unroll
            for (int r = 0; r < 4; ++r) {
                int m = m0 + wr + mt * 16 + quad * 4 + r;
                out[(size_t)m * 1024 + c] = acc[mt][nt][r] + bias;
            }
    }
}

// ---------------------------------------------------------------------------
extern "C" void kernel_launch(void* const* d_in, const int* in_sizes, int n_in,
                              void* d_out, int out_size, void* d_ws, size_t ws_size,
                              hipStream_t stream)
{
    const float* x     = (const float*)d_in[0];
    const float* Wq    = (const float*)d_in[1];
    const float* Wk    = (const float*)d_in[2];
    const float* Wv    = (const float*)d_in[3];
    const float* Wp    = (const float*)d_in[4];
    const float* bp    = (const float*)d_in[5];
    const float* cache = (const float*)d_in[6];
    float* outp = (float*)d_out;

    __bf16* ws = (__bf16*)d_ws;
    __bf16* qw = ws;                                   // [B][H][P][D]
    __bf16* kw = qw + (size_t)BSZ * NH * SEQ * HD;     // [B][HKV][P][D]
    __bf16* vw = kw + (size_t)BSZ * NKV * SEQ * HD;    // [B][HKV][D][P]  (V^T)
    __bf16* at = vw + (size_t)BSZ * NKV * SEQ * HD;    // [B][P][H*D]
    float* mags_b = (float*)(at + (size_t)BSZ * NH * SEQ * HD);  // 32 floats
    int*   kv_id  = (int*)(mags_b + 32);                          // 16 ints

    qkv_gemm<<<dim3(16, 64), 256, 0, stream>>>(x, Wq, Wk, Wv, qw, kw, vw);
    ksumsq<<<32, 256, 0, stream>>>(kw, mags_b);
    ratios_kernel<<<1, 64, 0, stream>>>(mags_b, cache, kv_id);
    attn_kernel<<<dim3(16, 64), 256, 0, stream>>>(qw, kw, vw, kv_id, at);
    proj_gemm<<<dim3(8, 64), 256, 0, stream>>>(at, Wp, bp, outp);
}